// Round 13
// baseline (51.027 us; speedup 1.0000x reference)
//
#include <hip/hip_runtime.h>
#include <hip/hip_bf16.h>

#define NCLS 13
#define NBUF 3                 // wave-private triple buffer, 2-deep prefetch
#define RPT 4                  // rows per wave-tile
#define TPW 16                 // tiles per wave  -> 64 rows per wave
#define BLOCK 256              // 4 waves -> 256 rows per block
#define CWT (RPT * NCLS * NCLS)   // 676 floats C per wave-tile
#define XWT (RPT * NCLS)          // 52 floats x (or s) per wave-tile

// async global->LDS DMA, 16B/lane; HW writes LDS at uniform base + lane*16
__device__ __forceinline__ void async_cp16(const float* g, float* l) {
    __builtin_amdgcn_global_load_lds(
        (__attribute__((address_space(1))) void*)(const_cast<float*>(g)),
        (__attribute__((address_space(3))) void*)(l),
        16, 0, 0);
}

// same, with NT (non-temporal) cache policy: stream reads, no L2 allocate.
// gfx950 CPol: SC0=1, NT=2, SC1=16.
__device__ __forceinline__ void async_cp16_nt(const float* g, float* l) {
    __builtin_amdgcn_global_load_lds(
        (__attribute__((address_space(1))) void*)(const_cast<float*>(g)),
        (__attribute__((address_space(3))) void*)(l),
        16, 0, 2);
}

__global__ __launch_bounds__(BLOCK) void rnorm_kernel(
    const float* __restrict__ input,
    const int* __restrict__ target,
    const float* __restrict__ s,
    const float* __restrict__ C,
    float* __restrict__ out)
{
    // wave-private buffers: 4 waves * 3 bufs * (2704+208+208) B = 37440 B -> 4 blocks/CU
    __shared__ __align__(16) float cbuf[4][NBUF][CWT];
    __shared__ __align__(16) float xbuf[4][NBUF][XWT];
    __shared__ __align__(16) float sbuf[4][NBUF][XWT];
    __shared__ float wsum[4];

    const int tid  = threadIdx.x;
    const int w    = tid >> 6;     // wave 0..3
    const int lane = tid & 63;
    const int rloc = lane >> 4;    // 0..3: row within wave-tile
    const int q    = lane & 15;    // 16 lanes per row, 13 active

    const int w0 = blockIdx.x * (BLOCK) + w * (RPT * TPW);  // wave's first row (64 rows/wave)

    // preload this wave's 64 targets, one per lane; pin so its vmcnt wait
    // happens HERE and never pollutes the counted DMA stream below.
    int trg = target[w0 + lane];
    asm volatile("" : "+v"(trg));

    // exactly 5 DMA instructions per wave-tile (per-wave vmcnt accounting)
    auto stage = [&](int t_idx, int buf) {
        const int r0 = w0 + t_idx * RPT;
        const float4* Cg = (const float4*)(C + (size_t)r0 * (NCLS * NCLS));
        float* cd = &cbuf[w][buf][0];
        async_cp16_nt((const float*)(Cg + lane),       cd + (size_t)lane * 4);
        async_cp16_nt((const float*)(Cg + 64 + lane),  cd + (size_t)(64 + lane) * 4);
        if (lane < CWT / 4 - 128)   // 169 f4 = 64 + 64 + 41
            async_cp16_nt((const float*)(Cg + 128 + lane), cd + (size_t)(128 + lane) * 4);
        const float4* xg = (const float4*)(input + (size_t)r0 * NCLS);
        if (lane < XWT / 4)
            async_cp16((const float*)(xg + lane), &xbuf[w][buf][0] + (size_t)lane * 4);
        const float4* sg = (const float4*)(s + (size_t)r0 * NCLS);
        if (lane < XWT / 4)
            async_cp16((const float*)(sg + lane), &sbuf[w][buf][0] + (size_t)lane * 4);
    };

    float res_acc = 0.0f;

    // prologue: 2-deep prefetch
    stage(0, 0);
    stage(1, 1);
    asm volatile("s_waitcnt vmcnt(5)" ::: "memory");   // tile 0 landed, tile 1 in flight
    __builtin_amdgcn_sched_barrier(0);

    for (int t = 0; t < TPW; ++t) {
        const int bcur = t % NBUF;
        if (t + 2 < TPW)
            stage(t + 2, (t + 2) % NBUF);

        // ---- compute tile t from wave-private LDS ----
        const float* cbt = cbuf[w][bcur];
        const float* xbt = xbuf[w][bcur];
        const float* sbt = sbuf[w][bcur];
        const int tt = __shfl(trg, t * RPT + rloc);   // target of this lane's row

        float sp = 0.0f, sy = 0.0f, dd = 0.0f;
        if (q < NCLS) {
            const float* crow = cbt + rloc * (NCLS * NCLS) + q * NCLS;
            const float* xrow = xbt + rloc * NCLS;
            float zye = 0.0f;
#pragma unroll
            for (int j = 0; j < NCLS; ++j)
                zye = fmaf(crow[j], xrow[j], zye);
            const float zpe = crow[tt];               // one-hot column
            const float svi = sbt[rloc * NCLS + q];
            const float zp = svi - zpe, zy = svi - zye;
            sp = zp * zp; sy = zy * zy; dd = zy * zp;
        }

        sp += __shfl_xor(sp, 1); sp += __shfl_xor(sp, 2);
        sp += __shfl_xor(sp, 4); sp += __shfl_xor(sp, 8);
        sy += __shfl_xor(sy, 1); sy += __shfl_xor(sy, 2);
        sy += __shfl_xor(sy, 4); sy += __shfl_xor(sy, 8);
        dd += __shfl_xor(dd, 1); dd += __shfl_xor(dd, 2);
        dd += __shfl_xor(dd, 4); dd += __shfl_xor(dd, 8);

        if (q == 0)
            res_acc += sqrtf(sp) - dd / sqrtf(sy);

        // counted wait: tile t+1 landed; tile t+2 stays in flight. NO barrier.
        if (t + 1 < TPW) {
            if (t + 2 < TPW) asm volatile("s_waitcnt vmcnt(5)" ::: "memory");
            else             asm volatile("s_waitcnt vmcnt(0)" ::: "memory");
            __builtin_amdgcn_sched_barrier(0);
        }
    }

    // ---- block reduction ----
#pragma unroll
    for (int off = 32; off > 0; off >>= 1)
        res_acc += __shfl_down(res_acc, off, 64);

    if (lane == 0) wsum[w] = res_acc;
    __syncthreads();
    if (tid == 0)
        atomicAdd(out, wsum[0] + wsum[1] + wsum[2] + wsum[3]);
}

extern "C" void kernel_launch(void* const* d_in, const int* in_sizes, int n_in,
                              void* d_out, int out_size, void* d_ws, size_t ws_size,
                              hipStream_t stream) {
    const float* input  = (const float*)d_in[0];
    const int*   target = (const int*)d_in[1];   // harness passes integers as int32
    const float* s      = (const float*)d_in[2];
    const float* C      = (const float*)d_in[3];
    // d_in[4] (instance_weights) is unused by the reference.

    float* out = (float*)d_out;
    int N = in_sizes[1];                          // 262144

    // harness poisons d_out and does not re-zero between replays
    hipMemsetAsync(out, 0, sizeof(float) * out_size, stream);

    const int grid = N / BLOCK;                   // 1024 blocks, 256 rows each, exact
    rnorm_kernel<<<grid, BLOCK, 0, stream>>>(input, target, s, C, out);
}